// Round 9
// baseline (35.297 us; speedup 1.0000x reference)
//
#include <hip/hip_runtime.h>

#define D0 1024
#define D1 512
#define D2 256
#define NROWSUM (D0 + D1)

typedef float f32x4 __attribute__((ext_vector_type(4)));

// Kernel 1: row sums of W0 (1024x512) and W1 (512x256) -> s[1536].
// pred[b,i] = avg[b]*rowsum(W)[i] since cur is a [B,1] broadcast (state
// collapses to scalars per row). f32 accumulate (spike margins ~4x threshold;
// f64 not needed — halves the DS-pipe cost of the butterfly).
__global__ __launch_bounds__(256) void snn_rowsum(const float* __restrict__ W0,
                                                  const float* __restrict__ W1,
                                                  float* __restrict__ s) {
    const int lane = threadIdx.x & 63;
    const int wid  = threadIdx.x >> 6;
    const int row  = blockIdx.x * 4 + wid;
    if (row >= NROWSUM) return;
    const f32x4* base;
    int n4;
    if (row < D0) { base = (const f32x4*)(W0 + (size_t)row * D1);        n4 = D1 / 4; }
    else          { base = (const f32x4*)(W1 + (size_t)(row - D0) * D2); n4 = D2 / 4; }
    float acc = 0.0f;
    for (int j = lane; j < n4; j += 64) {
        const f32x4 v = base[j];
        acc += (v.x + v.y) + (v.z + v.w);
    }
    #pragma unroll
    for (int off = 32; off >= 1; off >>= 1) acc += __shfl_xor(acc, off, 64);
    if (lane == 0) s[row] = acc;
}

// Kernel 2: 2 batch rows per wave. FAST PATH: while a0,a1 stay in {0,1}
// (always true here — margins ~4x threshold), currents take table values:
//   cur0(a0=0) = G0/512,  cur0(a0=1) = G1/512   (G0=Sum|x|, G1=Sum|x-s0|)
//   cur1(0,0)=0, cur1(1,0)=2, cur1(0,1)=2*mean|s1|, cur1(1,1)=2*mean|1-s1|
// => ONE feature pass + ONE 4-sum butterfly per pair, scalar t-loop (exits
// after ~2 steps at the exact fixed point a=1,v=0).
// GUARD: if any a leaves {0,1}, rerun the general per-t path from t=0.
// x loads are issued FIRST (the 134 MB long pole); s loads follow and their
// latency hides under the G0 computation.
__global__ __launch_bounds__(256) void snn_main(const float* __restrict__ x,
                                                const float* __restrict__ s,
                                                const int* __restrict__ ts_ptr,
                                                float* __restrict__ out,
                                                int B) {
    const int lane = threadIdx.x & 63;
    const int wid  = threadIdx.x >> 6;
    const int pair = blockIdx.x * 4 + wid;
    const int P    = (B + 1) >> 1;
    if (pair >= P) return;
    const int  b0   = pair * 2;
    const bool has2 = (b0 + 1) < B;
    const int  b1   = has2 ? b0 + 1 : b0;

    // ---- issue the streaming x loads first ----
    const f32x4* xv0 = (const f32x4*)(x + (size_t)b0 * D0);
    const f32x4* xv1 = (const f32x4*)(x + (size_t)b1 * D0);
    f32x4 xa[4], xb[4];
    #pragma unroll
    for (int k = 0; k < 4; ++k) xa[k] = xv0[k * 64 + lane];
    #pragma unroll
    for (int k = 0; k < 4; ++k) xb[k] = xv1[k * 64 + lane];

    // ---- then the cached s fragments ----
    const f32x4* sv = (const f32x4*)s;
    f32x4 s0k[4], s1k[2];
    #pragma unroll
    for (int k = 0; k < 4; ++k) s0k[k] = sv[k * 64 + lane];
    #pragma unroll
    for (int k = 0; k < 2; ++k) s1k[k] = sv[D0 / 4 + k * 64 + lane];
    const int TS = *ts_ptr;

    // per-wave layer-1 constants: 2*mean|s1|, 2*mean|1-s1|  (512 terms / 256)
    float u0 = 0.f, u1 = 0.f;
    #pragma unroll
    for (int k = 0; k < 2; ++k) {
        u0 += fabsf(s1k[k].x) + fabsf(s1k[k].y) + fabsf(s1k[k].z) + fabsf(s1k[k].w);
        u1 += fabsf(1.0f - s1k[k].x) + fabsf(1.0f - s1k[k].y)
            + fabsf(1.0f - s1k[k].z) + fabsf(1.0f - s1k[k].w);
    }
    #pragma unroll
    for (int off = 32; off >= 1; off >>= 1) {
        u0 += __shfl_xor(u0, off, 64);
        u1 += __shfl_xor(u1, off, 64);
    }
    const float cur1_01 = u0 * (1.0f / 256.0f);   // a0=0, a1=1
    const float cur1_11 = u1 * (1.0f / 256.0f);   // a0=1, a1=1

    // one feature pass: G0=Sum|x|, G1=Sum|x-s0| for both rows
    float ga0 = 0.f, ga1 = 0.f, gb0 = 0.f, gb1 = 0.f;
    #pragma unroll
    for (int k = 0; k < 4; ++k) {
        ga0 += fabsf(xa[k].x) + fabsf(xa[k].y) + fabsf(xa[k].z) + fabsf(xa[k].w);
        gb0 += fabsf(xb[k].x) + fabsf(xb[k].y) + fabsf(xb[k].z) + fabsf(xb[k].w);
        ga1 += fabsf(xa[k].x - s0k[k].x) + fabsf(xa[k].y - s0k[k].y)
             + fabsf(xa[k].z - s0k[k].z) + fabsf(xa[k].w - s0k[k].w);
        gb1 += fabsf(xb[k].x - s0k[k].x) + fabsf(xb[k].y - s0k[k].y)
             + fabsf(xb[k].z - s0k[k].z) + fabsf(xb[k].w - s0k[k].w);
    }
    #pragma unroll
    for (int off = 32; off >= 1; off >>= 1) {
        ga0 += __shfl_xor(ga0, off, 64);
        ga1 += __shfl_xor(ga1, off, 64);
        gb0 += __shfl_xor(gb0, off, 64);
        gb1 += __shfl_xor(gb1, off, 64);
    }
    const float c0a0 = ga0 * (1.0f / 512.0f), c0a1 = ga1 * (1.0f / 512.0f);
    const float c0b0 = gb0 * (1.0f / 512.0f), c0b1 = gb1 * (1.0f / 512.0f);

    // ---------------- fast scalar t-loop ----------------
    float v0a = 0.f, a0a = 0.f, v1a = 0.f, a1a = 0.f;
    float v0b = 0.f, a0b = 0.f, v1b = 0.f, a1b = 0.f;
    bool fallback = false;

    for (int t = 0; t < TS; ++t) {
        const bool okA = (a0a == 0.f || a0a == 1.f) && (a1a == 0.f || a1a == 1.f);
        const bool okB = (a0b == 0.f || a0b == 1.f) && (a1b == 0.f || a1b == 1.f);
        if (!(okA && okB)) { fallback = true; break; }
        const float tf = (float)t;
        const float a0a_s = a0a, a1a_s = a1a, a0b_s = a0b, a1b_s = a1b;

        const float cur0a = (a0a == 1.f) ? c0a1 : c0a0;
        const float cur0b = (a0b == 1.f) ? c0b1 : c0b0;
        v0a = 0.5f * v0a + cur0a;
        v0b = 0.5f * v0b + cur0b;
        const float sp0a = (v0a >= 1.0f) ? 1.0f : 0.0f;
        const float sp0b = (v0b >= 1.0f) ? 1.0f : 0.0f;
        v0a = (v0a >= 1.0f) ? 0.0f : v0a;
        v0b = (v0b >= 1.0f) ? 0.0f : v0b;
        a0a = (a0a * tf + sp0a) / (tf + 1.0f);
        a0b = (a0b * tf + sp0b) / (tf + 1.0f);

        if (!((a0a == 0.f || a0a == 1.f) && (a0b == 0.f || a0b == 1.f))) {
            fallback = true; break;
        }
        const float cur1a = (a0a == 1.f) ? ((a1a == 1.f) ? cur1_11 : 2.0f)
                                         : ((a1a == 1.f) ? cur1_01 : 0.0f);
        const float cur1b = (a0b == 1.f) ? ((a1b == 1.f) ? cur1_11 : 2.0f)
                                         : ((a1b == 1.f) ? cur1_01 : 0.0f);
        v1a = 0.5f * v1a + cur1a;
        v1b = 0.5f * v1b + cur1b;
        const float sp1a = (v1a >= 1.0f) ? 1.0f : 0.0f;
        const float sp1b = (v1b >= 1.0f) ? 1.0f : 0.0f;
        v1a = (v1a >= 1.0f) ? 0.0f : v1a;
        v1b = (v1b >= 1.0f) ? 0.0f : v1b;
        a1a = (a1a * tf + sp1a) / (tf + 1.0f);
        a1b = (a1b * tf + sp1b) / (tf + 1.0f);

        // exact fixed point: a==1 entering + spike now => future steps identical
        const bool doneA = (a0a_s == 1.0f) && (sp0a == 1.0f) && (a1a_s == 1.0f) && (sp1a == 1.0f);
        const bool doneB = (a0b_s == 1.0f) && (sp0b == 1.0f) && (a1b_s == 1.0f) && (sp1b == 1.0f);
        if (doneA && (doneB || !has2)) break;
    }

    // ---------------- general fallback (never taken for this data) ----------
    if (fallback) {
        v0a = 0.f; a0a = 0.f; v1a = 0.f; a1a = 0.f;
        v0b = 0.f; a0b = 0.f; v1b = 0.f; a1b = 0.f;
        for (int t = 0; t < TS; ++t) {
            const float tf = (float)t;
            const float fa = a0a, fb = a0b;
            float pa = 0.f, pb = 0.f;
            #pragma unroll
            for (int k = 0; k < 4; ++k) {
                pa += fabsf(fmaf(-fa, s0k[k].x, xa[k].x)) + fabsf(fmaf(-fa, s0k[k].y, xa[k].y))
                    + fabsf(fmaf(-fa, s0k[k].z, xa[k].z)) + fabsf(fmaf(-fa, s0k[k].w, xa[k].w));
                pb += fabsf(fmaf(-fb, s0k[k].x, xb[k].x)) + fabsf(fmaf(-fb, s0k[k].y, xb[k].y))
                    + fabsf(fmaf(-fb, s0k[k].z, xb[k].z)) + fabsf(fmaf(-fb, s0k[k].w, xb[k].w));
            }
            #pragma unroll
            for (int off = 32; off >= 1; off >>= 1) {
                pa += __shfl_xor(pa, off, 64);
                pb += __shfl_xor(pb, off, 64);
            }
            v0a = 0.5f * v0a + pa * (1.0f / 512.0f);
            v0b = 0.5f * v0b + pb * (1.0f / 512.0f);
            const float sp0a = (v0a >= 1.0f) ? 1.0f : 0.0f;
            const float sp0b = (v0b >= 1.0f) ? 1.0f : 0.0f;
            v0a = (v0a >= 1.0f) ? 0.0f : v0a;
            v0b = (v0b >= 1.0f) ? 0.0f : v0b;
            a0a = (a0a * tf + sp0a) / (tf + 1.0f);
            a0b = (a0b * tf + sp0b) / (tf + 1.0f);

            const float ga = a1a, gb = a1b;
            const float na = a0a, nb = a0b;
            float qa = 0.f, qb = 0.f;
            #pragma unroll
            for (int k = 0; k < 2; ++k) {
                qa += fabsf(fmaf(-ga, s1k[k].x, na)) + fabsf(fmaf(-ga, s1k[k].y, na))
                    + fabsf(fmaf(-ga, s1k[k].z, na)) + fabsf(fmaf(-ga, s1k[k].w, na));
                qb += fabsf(fmaf(-gb, s1k[k].x, nb)) + fabsf(fmaf(-gb, s1k[k].y, nb))
                    + fabsf(fmaf(-gb, s1k[k].z, nb)) + fabsf(fmaf(-gb, s1k[k].w, nb));
            }
            #pragma unroll
            for (int off = 32; off >= 1; off >>= 1) {
                qa += __shfl_xor(qa, off, 64);
                qb += __shfl_xor(qb, off, 64);
            }
            v1a = 0.5f * v1a + qa * (1.0f / 256.0f);
            v1b = 0.5f * v1b + qb * (1.0f / 256.0f);
            const float sp1a = (v1a >= 1.0f) ? 1.0f : 0.0f;
            const float sp1b = (v1b >= 1.0f) ? 1.0f : 0.0f;
            v1a = (v1a >= 1.0f) ? 0.0f : v1a;
            v1b = (v1b >= 1.0f) ? 0.0f : v1b;
            a1a = (a1a * tf + sp1a) / (tf + 1.0f);
            a1b = (a1b * tf + sp1b) / (tf + 1.0f);
        }
    }

    // broadcast result across 256 output features; one f32x4 per lane
    {
        f32x4 rv; rv.x = a1a; rv.y = a1a; rv.z = a1a; rv.w = a1a;
        f32x4* ov = (f32x4*)(out + (size_t)b0 * D2);
        __builtin_nontemporal_store(rv, &ov[lane]);
    }
    if (has2) {
        f32x4 rv; rv.x = a1b; rv.y = a1b; rv.z = a1b; rv.w = a1b;
        f32x4* ov = (f32x4*)(out + (size_t)b1 * D2);
        __builtin_nontemporal_store(rv, &ov[lane]);
    }
}

extern "C" void kernel_launch(void* const* d_in, const int* in_sizes, int n_in,
                              void* d_out, int out_size, void* d_ws, size_t ws_size,
                              hipStream_t stream) {
    const float* x  = (const float*)d_in[0];
    const float* W0 = (const float*)d_in[1];
    const float* W1 = (const float*)d_in[2];
    const int*   ts = (const int*)d_in[3];
    float* out = (float*)d_out;
    float* s   = (float*)d_ws;   // s[0..1024) = rowsum(W0), s[1024..1536) = rowsum(W1)
    const int B = in_sizes[0] / D0;
    const int P = (B + 1) >> 1;

    snn_rowsum<<<(NROWSUM + 3) / 4, 256, 0, stream>>>(W0, W1, s);
    snn_main<<<(P + 3) / 4, 256, 0, stream>>>(x, s, ts, out, B);
}